// Round 3
// baseline (316.973 us; speedup 1.0000x reference)
//
#include <hip/hip_runtime.h>
#include <math.h>

#define HN       250
#define WN       400
#define N_RAYS   (HN * WN)        // 100000
#define N_SAMP   1000000
#define P_TENSO  50000
#define STEP_SZ  0.005f
#define DENS_SCALE 1.0f           // min(1/(1-0), 25) = 1
#define NB_SCAN  ((P_TENSO + 1023) / 1024)   // 49

// NOTE (R7): cooperative grid.sync() measured ~100 us/sync on MI355X — do not
// re-fuse with cooperative launch. NOTE (R8): each device-scope returning
// atomicAdd costs a 64B line transaction (1M atomics == 64 MB WRITE_SIZE).
// NOTE (R9/R10 measurements): gather_phase is LATENCY-bound, not BW-bound —
// random vs coalesced loads AND scatter vs coalesced stores all measure ~55us.
// 2x sample unroll HURT (60us: VGPR 32->36, occ 70->62). Scattered 32B stores
// in a thin kernel cost ~14us. => keep gather at 16 samples/trip; put ALL
// random traffic inside gather; keep thin kernels lean (R11: pack eliminated,
// gather reads raw g-arrays; quad-parallel ray_render).

// ---------------- workspace layout (bytes) ----------------
#define OFF_RESULTS 0            // 1M x 16B (lt,r,g,b), ORIGINAL (n) order
#define OFF_PERM    16000000     // 1M int, pos -> n
#define OFF_RT      20000000     // 1M int, (tid<<16)|rank
#define OFF_CURSOR  24000000     // 50K int (atomic counters == final counts)
#define OFF_STARTS  24200000     // 50K int
#define OFF_BSUMS   24400000     // 64 int
#define OFF_FLAG    24400512     // 1 int (spin-barrier arrival)
#define OFF_RSTART  24401024     // (N_RAYS+1) int
#define WS_NEED     (24401024 + 400004 + 64)

// gather slab layout (floats), per wave
#define ROW_STRIDE 20                 // 16 ch + 4 pad
#define TV_F   (24 * ROW_STRIDE)      // 480
#define SLAB_F (TV_F + 16 + 48)       // 544

// ---------------------------------------------------------------------------
// A: rank via ONE returning atomic pass + ray bounds. R11: no payload packing
// at all — gather reads the raw arrays. rt fuses (tid,rank) into one word
// (rank < 65536 guaranteed: avg 20 samples/tid).
// ---------------------------------------------------------------------------
__global__ __launch_bounds__(256) void rank_bounds(
    const int* __restrict__ tenso_id,
    const int* __restrict__ ray_id,     // sorted
    int* __restrict__ cursor,           // zeroed; becomes counts
    int* __restrict__ rt,               // (tid<<16)|rank
    int* __restrict__ ray_start)
{
    int n = blockIdx.x * 256 + threadIdx.x;
    if (n >= N_SAMP) return;

    const int tid = tenso_id[n];
    const int rk = atomicAdd(&cursor[tid], 1);     // the single atomic pass
    rt[n] = (tid << 16) | rk;

    int r = ray_id[n];
    int rprev = (n == 0) ? -1 : ray_id[n - 1];
    for (int q = rprev + 1; q <= r; ++q) ray_start[q] = n;
    if (n == N_SAMP - 1) {
        for (int q = r + 1; q <= N_RAYS; ++q) ray_start[q] = N_SAMP;
    }
}

// ---------------------------------------------------------------------------
// B: fused exclusive scan of counts -> starts. 49 blocks (co-resident on 256
// CUs), internal spin barrier on an arrival counter.
// ---------------------------------------------------------------------------
__global__ __launch_bounds__(256) void scan_fused(
    const int* __restrict__ cursor,   // counts
    int* __restrict__ starts,
    int* __restrict__ bsums,
    int* __restrict__ flag)
{
    __shared__ int lds[257];
    const int b = blockIdx.x;
    const int t = threadIdx.x;
    const int base = b * 1024 + t * 4;

    int v[4]; int s = 0;
    #pragma unroll
    for (int i = 0; i < 4; ++i) {
        int idx = base + i;
        v[i] = (idx < P_TENSO) ? cursor[idx] : 0;
        s += v[i];
    }
    lds[t] = s;
    __syncthreads();
    for (int d = 1; d < 256; d <<= 1) {
        int x = (t >= d) ? lds[t - d] : 0;
        __syncthreads();
        lds[t] += x;
        __syncthreads();
    }
    if (t == 255) bsums[b] = lds[255];

    // ---- barrier across the 49 blocks ----
    __threadfence();
    __syncthreads();
    if (t == 0) {
        atomicAdd(flag, 1);
        while (atomicAdd(flag, 0) < gridDim.x) { }
    }
    __syncthreads();
    __threadfence();

    // every block computes its global prefix = sum of bsums[0..b)
    if (t < 64) {
        int x = (t < b) ? bsums[t] : 0;
        #pragma unroll
        for (int m = 1; m < 64; m <<= 1) x += __shfl_xor(x, m);
        if (t == 0) lds[256] = x;
    }
    __syncthreads();
    const int pre = lds[256];

    int run = pre + ((t > 0) ? lds[t - 1] : 0);
    #pragma unroll
    for (int i = 0; i < 4; ++i) {
        int idx = base + i;
        if (idx < P_TENSO) starts[idx] = run;
        run += v[i];
    }
}

// ---------------------------------------------------------------------------
// C: positions without atomics: pos = starts[tid] + rank. Reads only rt (4MB).
// ---------------------------------------------------------------------------
__global__ __launch_bounds__(256) void finalize_perm(
    const int* __restrict__ rt,
    const int* __restrict__ starts,
    int* __restrict__ perm)
{
    int n = blockIdx.x * 256 + threadIdx.x;
    if (n >= N_SAMP) return;
    const unsigned w = (unsigned)rt[n];
    int pos = starts[w >> 16] + (int)(w & 0xFFFFu);
    perm[pos] = n;           // random 4B into 4MB (L2-resident)
}

// ---------------------------------------------------------------------------
// Gather: one wave per tensoRF id; lanes = 16 samples x 4 channel-groups.
// R11: reads raw gis/gil/gws/gwl via perm (random, measured-free in this
// latency-bound kernel); scatter-writes results to ORIGINAL n order
// (measured-free) so ray_render streams. 16 samples/trip (unroll reverted).
// ---------------------------------------------------------------------------
__global__ __launch_bounds__(256) void gather_phase(
    const float* __restrict__ trivecs,   // (P,16,3,8)
    const float* __restrict__ densities, // (P,16)
    const float* __restrict__ colors,    // (P,16,3)
    const int*   __restrict__ starts,
    const int*   __restrict__ counts,    // == cursor
    const int*   __restrict__ perm,
    const int*   __restrict__ gis, const int* __restrict__ gil,
    const float* __restrict__ gws, const float* __restrict__ gwl,
    float* __restrict__ results_f)       // [n*4 + j], original order
{
    __shared__ __align__(16) float lds[4 * SLAB_F];
    const int lane = threadIdx.x & 63;
    const int wv   = threadIdx.x >> 6;
    const int t    = blockIdx.x * 4 + wv;
    if (t >= P_TENSO) return;

    const int start = starts[t];
    const int cnt   = counts[t];
    if (cnt == 0) return;

    float* slab = lds + wv * SLAB_F;
    float* dl   = slab + TV_F;
    float* cl   = dl + 16;

    const int g = lane >> 2;   // sample slot 0..15
    const int j = lane & 3;    // channel group
    const int end = start + cnt;

    // trip-0 perm load issued before staging (flies under the slab loads)
    int p = start + g;
    int n = perm[(p < end) ? p : (end - 1)];

    const float* tvg = trivecs + (size_t)t * 384;
    #pragma unroll
    for (int i = 0; i < 6; ++i) {
        int l = lane + i * 64;
        int c = l / 24;
        int rem = l - c * 24;
        slab[rem * ROW_STRIDE + c] = tvg[l];
    }
    if (lane < 16) dl[lane] = densities[(size_t)t * 16 + lane];
    if (lane < 48) {
        int c = lane / 3, k = lane - c * 3;
        cl[k * 16 + c] = colors[(size_t)t * 48 + lane];
    }

    const float4 dens4 = *(const float4*)(dl + 4 * j);
    const float4 col0  = *(const float4*)(cl + 4 * j);
    const float4 col1  = *(const float4*)(cl + 16 + 4 * j);
    const float4 col2  = *(const float4*)(cl + 32 + 4 * j);

    const int niter = (cnt + 15) >> 4;

    for (int it = 0; it < niter; ++it) {
        const bool valid = (p < end);
        const int sn = n;                 // saved for the store
        const int b3 = sn * 3;

        // raw per-sample loads (random, latency-tolerant here)
        const int   is0 = gis[b3], is1 = gis[b3 + 1], is2 = gis[b3 + 2];
        const int   il0 = gil[b3], il1 = gil[b3 + 1], il2 = gil[b3 + 2];
        const float wa0 = gws[b3], wa1 = gws[b3 + 1], wa2 = gws[b3 + 2];
        const float wb0 = gwl[b3], wb1 = gwl[b3 + 1], wb2 = gwl[b3 + 2];

        if (it + 1 < niter) {             // prefetch next trip's perm
            p = start + (it + 1) * 16 + g;
            n = perm[(p < end) ? p : (end - 1)];
        }

        float4 f;
        {
            const float4 vs = *(const float4*)(slab + is0 * ROW_STRIDE + 4 * j);
            const float4 vl = *(const float4*)(slab + il0 * ROW_STRIDE + 4 * j);
            f.x = vs.x * wa0 + vl.x * wb0;
            f.y = vs.y * wa0 + vl.y * wb0;
            f.z = vs.z * wa0 + vl.z * wb0;
            f.w = vs.w * wa0 + vl.w * wb0;
        }
        {
            const float4 vs = *(const float4*)(slab + (8 + is1) * ROW_STRIDE + 4 * j);
            const float4 vl = *(const float4*)(slab + (8 + il1) * ROW_STRIDE + 4 * j);
            f.x *= vs.x * wa1 + vl.x * wb1;
            f.y *= vs.y * wa1 + vl.y * wb1;
            f.z *= vs.z * wa1 + vl.z * wb1;
            f.w *= vs.w * wa1 + vl.w * wb1;
        }
        {
            const float4 vs = *(const float4*)(slab + (16 + is2) * ROW_STRIDE + 4 * j);
            const float4 vl = *(const float4*)(slab + (16 + il2) * ROW_STRIDE + 4 * j);
            f.x *= vs.x * wa2 + vl.x * wb2;
            f.y *= vs.y * wa2 + vl.y * wb2;
            f.z *= vs.z * wa2 + vl.z * wb2;
            f.w *= vs.w * wa2 + vl.w * wb2;
        }

        float s0 = f.x * dens4.x + f.y * dens4.y + f.z * dens4.z + f.w * dens4.w;
        float s1 = f.x * col0.x  + f.y * col0.y  + f.z * col0.z  + f.w * col0.w;
        float s2 = f.x * col1.x  + f.y * col1.y  + f.z * col1.z  + f.w * col1.w;
        float s3 = f.x * col2.x  + f.y * col2.y  + f.z * col2.z  + f.w * col2.w;

        s0 += __shfl_xor(s0, 1); s0 += __shfl_xor(s0, 2);
        s1 += __shfl_xor(s1, 1); s1 += __shfl_xor(s1, 2);
        s2 += __shfl_xor(s2, 1); s2 += __shfl_xor(s2, 2);
        s3 += __shfl_xor(s3, 1); s3 += __shfl_xor(s3, 2);

        const float sj = (j == 0) ? s0 : (j == 1) ? s1 : (j == 2) ? s2 : s3;
        float val;
        if (j == 0) {
            float dens = fmaxf(sj, 0.0f) + __logf(1.0f + __expf(-fabsf(sj)));
            val = -(dens * DENS_SCALE) * STEP_SZ;            // lt
        } else {
            val = 1.0f / (1.0f + __expf(-sj));               // sigmoid
        }
        if (valid) results_f[(size_t)sn * 4 + j] = val;      // 16B-granule scatter
    }
}

// ---------------------------------------------------------------------------
// E: 4 lanes per ray. Coalesced 64B loads per quad; quad prefix-product of
// exp(lt) via width-4 shfls (1 exp/lane/iter); ~3 iters instead of ~10.
// ---------------------------------------------------------------------------
__global__ __launch_bounds__(256) void ray_render(
    const float4* __restrict__ results,  // original n order
    const float*  __restrict__ t_min,
    const float*  __restrict__ bg,
    const int*    __restrict__ ray_start,
    const int*    __restrict__ step_id,
    float* __restrict__ out)
{
    const int lane = threadIdx.x & 63;
    const int g    = lane & 3;
    const int r    = (blockIdx.x * 256 + threadIdx.x) >> 2;
    if (r >= N_RAYS) return;
    const int s = ray_start[r];
    const int e = ray_start[r + 1];
    const float tmin_r = t_min[r];

    float eT = 1.0f, aR = 0.0f, aG = 0.0f, aB = 0.0f, aD = 0.0f;
    const int niter = (e - s + 3) >> 2;
    for (int it = 0; it < niter; ++it) {
        const int idx = s + it * 4 + g;
        const bool valid = (idx < e);
        const int ci = valid ? idx : (e - 1);
        const float4 res = results[ci];
        const float z = tmin_r + (float)step_id[ci] * STEP_SZ;
        const float elt = valid ? __expf(res.x) : 1.0f;   // exp(lt), 1 => w=0

        // exclusive prefix product of elt within the quad
        float excl = 1.0f;
        const float v1 = __shfl_up(elt, 1, 4); if (g >= 1) excl *= v1;
        const float v2 = __shfl_up(elt, 2, 4); if (g >= 2) excl *= v2;
        const float v3 = __shfl_up(elt, 3, 4); if (g >= 3) excl *= v3;

        const float w = eT * excl * (1.0f - elt);
        aR += w * res.y;
        aG += w * res.z;
        aB += w * res.w;
        aD += w * z;

        const float tot = __shfl(excl * elt, 3, 4);  // product of all 4 elts
        eT *= tot;
    }

    // quad reduction of accumulators
    aR += __shfl_xor(aR, 1); aR += __shfl_xor(aR, 2);
    aG += __shfl_xor(aG, 1); aG += __shfl_xor(aG, 2);
    aB += __shfl_xor(aB, 1); aB += __shfl_xor(aB, 2);
    aD += __shfl_xor(aD, 1); aD += __shfl_xor(aD, 2);

    const float outv = (g == 0) ? aR + eT * bg[0]
                     : (g == 1) ? aG + eT * bg[1]
                     : (g == 2) ? aB + eT * bg[2]
                     : aD;
    out[g * N_RAYS + r] = outv;
    if (g == 0) out[4 * N_RAYS + r] = 1.0f - eT;
}

// ---------------------------------------------------------------------------
// Fallback (ws too small): single fused kernel, original layouts.
// ---------------------------------------------------------------------------
__global__ __launch_bounds__(256) void trivec_render_fallback(
    const float* __restrict__ trivecs, const float* __restrict__ densities,
    const float* __restrict__ colors, const float* __restrict__ gws,
    const float* __restrict__ gwl, const float* __restrict__ t_min,
    const float* __restrict__ bg, const int* __restrict__ gis,
    const int* __restrict__ gil, const int* __restrict__ tenso_id,
    const int* __restrict__ ray_id, const int* __restrict__ step_id,
    float* __restrict__ out)
{
    const int lane = threadIdx.x & 63;
    const int r = blockIdx.x * 4 + (threadIdx.x >> 6);
    if (r >= N_RAYS) return;
    const int c = lane & 15;
    const int g = lane >> 4;
    int lo = 0, hi = N_SAMP;
    while (lo < hi) { int mid = (lo + hi) >> 1; if (ray_id[mid] < r) lo = mid + 1; else hi = mid; }
    const int seg_start = lo;
    hi = N_SAMP;
    while (lo < hi) { int mid = (lo + hi) >> 1; if (ray_id[mid] < r + 1) lo = mid + 1; else hi = mid; }
    const int seg_end = lo;
    const float tmin_r = t_min[r];
    float Tlog = 0.0f, accR = 0.0f, accG = 0.0f, accB = 0.0f, accD = 0.0f;
    const int niter = (seg_end - seg_start + 3) >> 2;
    for (int it = 0; it < niter; ++it) {
        const int n = seg_start + it * 4 + g;
        const bool valid = (n < seg_end);
        const int nc = valid ? n : (seg_end - 1);
        const int tid = tenso_id[nc];
        const float* tv = trivecs + (size_t)tid * 384 + c * 24;
        float f = 1.0f;
        #pragma unroll
        for (int a = 0; a < 3; ++a) {
            const int is = gis[nc*3+a], il = gil[nc*3+a];
            const float wS = gws[nc*3+a], wL = gwl[nc*3+a];
            f *= (tv[a*8+is] * wS + tv[a*8+il] * wL);
        }
        const float dns = densities[(size_t)tid * 16 + c];
        const float* colp = colors + ((size_t)tid * 16 + c) * 3;
        float s0 = f*dns, s1 = f*colp[0], s2 = f*colp[1], s3 = f*colp[2];
        #pragma unroll
        for (int m = 1; m < 16; m <<= 1) {
            s0 += __shfl_xor(s0, m); s1 += __shfl_xor(s1, m);
            s2 += __shfl_xor(s2, m); s3 += __shfl_xor(s3, m);
        }
        float dens = fmaxf(s0, 0.0f) + __logf(1.0f + __expf(-fabsf(s0)));
        const float lt = valid ? (-dens * STEP_SZ) : 0.0f;
        const float alpha = 1.0f - __expf(lt);
        const float rr = 1.0f/(1.0f+__expf(-s1)), gg = 1.0f/(1.0f+__expf(-s2)), bb = 1.0f/(1.0f+__expf(-s3));
        const float z = tmin_r + (float)step_id[nc] * STEP_SZ;
        const float lt0 = __shfl(lt,0), lt1 = __shfl(lt,16), lt2 = __shfl(lt,32), lt3 = __shfl(lt,48);
        float excl = Tlog;
        if (g > 0) excl += lt0;
        if (g > 1) excl += lt1;
        if (g > 2) excl += lt2;
        const float w = alpha * __expf(excl);
        Tlog += lt0 + lt1 + lt2 + lt3;
        accR += w*rr; accG += w*gg; accB += w*bb; accD += w*z;
    }
    accR += __shfl_xor(accR,16); accR += __shfl_xor(accR,32);
    accG += __shfl_xor(accG,16); accG += __shfl_xor(accG,32);
    accB += __shfl_xor(accB,16); accB += __shfl_xor(accB,32);
    accD += __shfl_xor(accD,16); accD += __shfl_xor(accD,32);
    const float bgw = __expf(Tlog);
    if (lane == 0) {
        out[0*N_RAYS+r] = accR + bgw*bg[0];
        out[1*N_RAYS+r] = accG + bgw*bg[1];
        out[2*N_RAYS+r] = accB + bgw*bg[2];
        out[3*N_RAYS+r] = accD;
        out[4*N_RAYS+r] = 1.0f - bgw;
    }
}

extern "C" void kernel_launch(void* const* d_in, const int* in_sizes, int n_in,
                              void* d_out, int out_size, void* d_ws, size_t ws_size,
                              hipStream_t stream) {
    const float* trivecs   = (const float*)d_in[0];
    const float* densities = (const float*)d_in[1];
    const float* colors    = (const float*)d_in[2];
    const float* gws       = (const float*)d_in[3];
    const float* gwl       = (const float*)d_in[4];
    const float* t_min     = (const float*)d_in[5];
    const float* bg        = (const float*)d_in[6];
    const int*   gis       = (const int*)d_in[7];
    const int*   gil       = (const int*)d_in[8];
    const int*   tenso_id  = (const int*)d_in[9];
    const int*   ray_id    = (const int*)d_in[10];
    const int*   step_id   = (const int*)d_in[11];
    float* out = (float*)d_out;

    if (ws_size < (size_t)WS_NEED) {
        trivec_render_fallback<<<(N_RAYS + 3) / 4, 256, 0, stream>>>(
            trivecs, densities, colors, gws, gwl, t_min, bg,
            gis, gil, tenso_id, ray_id, step_id, out);
        return;
    }

    char* ws = (char*)d_ws;
    float4* results  = (float4*)(ws + OFF_RESULTS);
    int*    perm     = (int*)(ws + OFF_PERM);
    int*    rt       = (int*)(ws + OFF_RT);
    int*    cursor   = (int*)(ws + OFF_CURSOR);
    int*    starts   = (int*)(ws + OFF_STARTS);
    int*    bsums    = (int*)(ws + OFF_BSUMS);
    int*    flag     = (int*)(ws + OFF_FLAG);
    int*    raystart = (int*)(ws + OFF_RSTART);

    // zero cursor + starts + bsums + flag in one async memset
    hipMemsetAsync(ws + OFF_CURSOR, 0, (OFF_FLAG + 64) - OFF_CURSOR, stream);

    rank_bounds<<<(N_SAMP + 255) / 256, 256, 0, stream>>>(
        tenso_id, ray_id, cursor, rt, raystart);
    scan_fused<<<NB_SCAN, 256, 0, stream>>>(cursor, starts, bsums, flag);
    finalize_perm<<<(N_SAMP + 255) / 256, 256, 0, stream>>>(
        rt, starts, perm);
    gather_phase<<<(P_TENSO + 3) / 4, 256, 0, stream>>>(
        trivecs, densities, colors, starts, cursor, perm,
        gis, gil, gws, gwl, (float*)results);
    ray_render<<<(N_RAYS * 4 + 255) / 256, 256, 0, stream>>>(
        results, t_min, bg, raystart, step_id, out);
}

// Round 4
// 278.493 us; speedup vs baseline: 1.1382x; 1.1382x over previous
//
#include <hip/hip_runtime.h>
#include <math.h>

#define HN       250
#define WN       400
#define N_RAYS   (HN * WN)        // 100000
#define N_SAMP   1000000
#define P_TENSO  50000
#define STEP_SZ  0.005f
#define DENS_SCALE 1.0f           // min(1/(1-0), 25) = 1
#define NB_SCAN  ((P_TENSO + 1023) / 1024)   // 49

// NOTE (R7): cooperative grid.sync() ~100 us/sync on MI355X — don't re-fuse.
// NOTE (R8): each returning atomicAdd costs a 64B line transaction.
// NOTE (R9/R10): gather is LATENCY-bound; 32B-packed random loads and scatter
// stores are free INSIDE gather; scattered 32B stores in a thin kernel cost
// ~14us; 2x sample unroll HURT gather (VGPR 32->36, occ 70->62).
// NOTE (R11): "random loads are free" requires LINE-EFFICIENT packing: raw
// 4-array reads per sample = 4x64B lines/sample -> FETCH 108->300MB, gather
// 60->105us. The 32MB pack array earns its keep. Quad ray_render + rt fusion
// verified correct.

// ---------------- workspace layout (bytes) ----------------
#define OFF_PACK    0            // 1M x 32B sample structs, original (n) order
#define OFF_RESULTS 32000000     // 1M x 16B (lt,r,g,b), ORIGINAL (n) order
#define OFF_PERM    48000000     // 1M int, pos -> n
#define OFF_RT      52000000     // 1M int, (tid<<16)|rank
#define OFF_CURSOR  56000000     // 50K int (atomic counters == final counts)
#define OFF_STARTS  56200000     // 50K int
#define OFF_BSUMS   56400000     // 64 int
#define OFF_FLAG    56400512     // 1 int (spin-barrier arrival)
#define OFF_RSTART  56401024     // (N_RAYS+1) int
#define WS_NEED     (56401024 + 400004 + 64)

// gather slab layout (floats), per wave
#define ROW_STRIDE 20                 // 16 ch + 4 pad
#define TV_F   (24 * ROW_STRIDE)      // 480
#define SLAB_F (TV_F + 16 + 48)       // 544

// ---------------------------------------------------------------------------
// A: pack (coalesced 32B W) + ray bounds + rank via ONE returning atomic pass.
// rt fuses (tid,rank) into one word (rank < 65536: avg 20 samples/tid).
// ---------------------------------------------------------------------------
__global__ __launch_bounds__(256) void pack_bounds_rank(
    const int*   __restrict__ tenso_id,
    const int*   __restrict__ ray_id,     // sorted
    const int*   __restrict__ gis, const int* __restrict__ gil,
    const float* __restrict__ gws, const float* __restrict__ gwl,
    int* __restrict__ cursor,             // zeroed; becomes counts
    int* __restrict__ rt,                 // (tid<<16)|rank
    int* __restrict__ ray_start,
    float4* __restrict__ pack)
{
    int n = blockIdx.x * 256 + threadIdx.x;
    if (n >= N_SAMP) return;

    const int tid = tenso_id[n];
    const int rk = atomicAdd(&cursor[tid], 1);     // the single atomic pass
    rt[n] = (tid << 16) | rk;

    unsigned bits = (unsigned)gis[n*3+0] | ((unsigned)gis[n*3+1] << 3) | ((unsigned)gis[n*3+2] << 6)
                  | ((unsigned)gil[n*3+0] << 9) | ((unsigned)gil[n*3+1] << 12) | ((unsigned)gil[n*3+2] << 15);
    float4 A = make_float4(gws[n*3+0], gws[n*3+1], gws[n*3+2], gwl[n*3+0]);
    float4 B = make_float4(gwl[n*3+1], gwl[n*3+2], __uint_as_float(bits), 0.0f);
    pack[(size_t)n * 2 + 0] = A;
    pack[(size_t)n * 2 + 1] = B;

    int r = ray_id[n];
    int rprev = (n == 0) ? -1 : ray_id[n - 1];
    for (int q = rprev + 1; q <= r; ++q) ray_start[q] = n;
    if (n == N_SAMP - 1) {
        for (int q = r + 1; q <= N_RAYS; ++q) ray_start[q] = N_SAMP;
    }
}

// ---------------------------------------------------------------------------
// B: fused exclusive scan of counts -> starts. 49 blocks (co-resident on 256
// CUs), internal spin barrier on an arrival counter.
// ---------------------------------------------------------------------------
__global__ __launch_bounds__(256) void scan_fused(
    const int* __restrict__ cursor,   // counts
    int* __restrict__ starts,
    int* __restrict__ bsums,
    int* __restrict__ flag)
{
    __shared__ int lds[257];
    const int b = blockIdx.x;
    const int t = threadIdx.x;
    const int base = b * 1024 + t * 4;

    int v[4]; int s = 0;
    #pragma unroll
    for (int i = 0; i < 4; ++i) {
        int idx = base + i;
        v[i] = (idx < P_TENSO) ? cursor[idx] : 0;
        s += v[i];
    }
    lds[t] = s;
    __syncthreads();
    for (int d = 1; d < 256; d <<= 1) {
        int x = (t >= d) ? lds[t - d] : 0;
        __syncthreads();
        lds[t] += x;
        __syncthreads();
    }
    if (t == 255) bsums[b] = lds[255];

    // ---- barrier across the 49 blocks ----
    __threadfence();
    __syncthreads();
    if (t == 0) {
        atomicAdd(flag, 1);
        while (atomicAdd(flag, 0) < gridDim.x) { }
    }
    __syncthreads();
    __threadfence();

    // every block computes its global prefix = sum of bsums[0..b)
    if (t < 64) {
        int x = (t < b) ? bsums[t] : 0;
        #pragma unroll
        for (int m = 1; m < 64; m <<= 1) x += __shfl_xor(x, m);
        if (t == 0) lds[256] = x;
    }
    __syncthreads();
    const int pre = lds[256];

    int run = pre + ((t > 0) ? lds[t - 1] : 0);
    #pragma unroll
    for (int i = 0; i < 4; ++i) {
        int idx = base + i;
        if (idx < P_TENSO) starts[idx] = run;
        run += v[i];
    }
}

// ---------------------------------------------------------------------------
// C: positions without atomics: pos = starts[tid] + rank. Reads only rt (4MB).
// ---------------------------------------------------------------------------
__global__ __launch_bounds__(256) void finalize_perm(
    const int* __restrict__ rt,
    const int* __restrict__ starts,
    int* __restrict__ perm)
{
    int n = blockIdx.x * 256 + threadIdx.x;
    if (n >= N_SAMP) return;
    const unsigned w = (unsigned)rt[n];
    int pos = starts[w >> 16] + (int)(w & 0xFFFFu);
    perm[pos] = n;           // random 4B into 4MB (L2-resident)
}

// ---------------------------------------------------------------------------
// Gather: one wave per tensoRF id; lanes = 16 samples x 4 channel-groups.
// 16 samples/trip (unroll measured harmful), perm prefetch one trip ahead.
// Reads perm->pack (random 32B, line-efficient, measured-free); scatter-writes
// results to ORIGINAL n order (measured-free) so ray_render streams.
// ---------------------------------------------------------------------------
__global__ __launch_bounds__(256) void gather_phase(
    const float* __restrict__ trivecs,   // (P,16,3,8)
    const float* __restrict__ densities, // (P,16)
    const float* __restrict__ colors,    // (P,16,3)
    const int*   __restrict__ starts,
    const int*   __restrict__ counts,    // == cursor
    const int*   __restrict__ perm,
    const float4* __restrict__ pack,
    float* __restrict__ results_f)       // [n*4 + j], original order
{
    __shared__ __align__(16) float lds[4 * SLAB_F];
    const int lane = threadIdx.x & 63;
    const int wv   = threadIdx.x >> 6;
    const int t    = blockIdx.x * 4 + wv;
    if (t >= P_TENSO) return;

    const int start = starts[t];
    const int cnt   = counts[t];
    if (cnt == 0) return;

    float* slab = lds + wv * SLAB_F;
    float* dl   = slab + TV_F;
    float* cl   = dl + 16;

    const int g = lane >> 2;   // sample slot 0..15
    const int j = lane & 3;    // channel group
    const int end = start + cnt;

    // trip-0 perm load issued before staging (flies under the slab loads)
    int p = start + g;
    int n = perm[(p < end) ? p : (end - 1)];

    const float* tvg = trivecs + (size_t)t * 384;
    #pragma unroll
    for (int i = 0; i < 6; ++i) {
        int l = lane + i * 64;
        int c = l / 24;
        int rem = l - c * 24;
        slab[rem * ROW_STRIDE + c] = tvg[l];
    }
    if (lane < 16) dl[lane] = densities[(size_t)t * 16 + lane];
    if (lane < 48) {
        int c = lane / 3, k = lane - c * 3;
        cl[k * 16 + c] = colors[(size_t)t * 48 + lane];
    }

    const float4 dens4 = *(const float4*)(dl + 4 * j);
    const float4 col0  = *(const float4*)(cl + 4 * j);
    const float4 col1  = *(const float4*)(cl + 16 + 4 * j);
    const float4 col2  = *(const float4*)(cl + 32 + 4 * j);

    const int niter = (cnt + 15) >> 4;

    for (int it = 0; it < niter; ++it) {
        const bool valid = (p < end);
        const int sn = n;                 // saved for the store

        const float4 A = pack[(size_t)sn * 2 + 0];   // random 32B, quad-bcast
        const float4 B = pack[(size_t)sn * 2 + 1];

        if (it + 1 < niter) {             // prefetch next trip's perm
            p = start + (it + 1) * 16 + g;
            n = perm[(p < end) ? p : (end - 1)];
        }

        const unsigned bits = __float_as_uint(B.z);

        float4 f;
        {
            const int is = bits & 7, il = (bits >> 9) & 7;
            const float4 vs = *(const float4*)(slab + is * ROW_STRIDE + 4 * j);
            const float4 vl = *(const float4*)(slab + il * ROW_STRIDE + 4 * j);
            f.x = vs.x * A.x + vl.x * A.w;
            f.y = vs.y * A.x + vl.y * A.w;
            f.z = vs.z * A.x + vl.z * A.w;
            f.w = vs.w * A.x + vl.w * A.w;
        }
        {
            const int is = (bits >> 3) & 7, il = (bits >> 12) & 7;
            const float4 vs = *(const float4*)(slab + (8 + is) * ROW_STRIDE + 4 * j);
            const float4 vl = *(const float4*)(slab + (8 + il) * ROW_STRIDE + 4 * j);
            f.x *= vs.x * A.y + vl.x * B.x;
            f.y *= vs.y * A.y + vl.y * B.x;
            f.z *= vs.z * A.y + vl.z * B.x;
            f.w *= vs.w * A.y + vl.w * B.x;
        }
        {
            const int is = (bits >> 6) & 7, il = (bits >> 15) & 7;
            const float4 vs = *(const float4*)(slab + (16 + is) * ROW_STRIDE + 4 * j);
            const float4 vl = *(const float4*)(slab + (16 + il) * ROW_STRIDE + 4 * j);
            f.x *= vs.x * A.z + vl.x * B.y;
            f.y *= vs.y * A.z + vl.y * B.y;
            f.z *= vs.z * A.z + vl.z * B.y;
            f.w *= vs.w * A.z + vl.w * B.y;
        }

        float s0 = f.x * dens4.x + f.y * dens4.y + f.z * dens4.z + f.w * dens4.w;
        float s1 = f.x * col0.x  + f.y * col0.y  + f.z * col0.z  + f.w * col0.w;
        float s2 = f.x * col1.x  + f.y * col1.y  + f.z * col1.z  + f.w * col1.w;
        float s3 = f.x * col2.x  + f.y * col2.y  + f.z * col2.z  + f.w * col2.w;

        s0 += __shfl_xor(s0, 1); s0 += __shfl_xor(s0, 2);
        s1 += __shfl_xor(s1, 1); s1 += __shfl_xor(s1, 2);
        s2 += __shfl_xor(s2, 1); s2 += __shfl_xor(s2, 2);
        s3 += __shfl_xor(s3, 1); s3 += __shfl_xor(s3, 2);

        const float sj = (j == 0) ? s0 : (j == 1) ? s1 : (j == 2) ? s2 : s3;
        float val;
        if (j == 0) {
            float dens = fmaxf(sj, 0.0f) + __logf(1.0f + __expf(-fabsf(sj)));
            val = -(dens * DENS_SCALE) * STEP_SZ;            // lt
        } else {
            val = 1.0f / (1.0f + __expf(-sj));               // sigmoid
        }
        if (valid) results_f[(size_t)sn * 4 + j] = val;      // 16B-granule scatter
    }
}

// ---------------------------------------------------------------------------
// E: 4 lanes per ray. Coalesced 64B loads per quad; quad prefix-product of
// exp(lt) via width-4 shfls (1 exp/lane/iter); ~3 iters instead of ~10.
// ---------------------------------------------------------------------------
__global__ __launch_bounds__(256) void ray_render(
    const float4* __restrict__ results,  // original n order
    const float*  __restrict__ t_min,
    const float*  __restrict__ bg,
    const int*    __restrict__ ray_start,
    const int*    __restrict__ step_id,
    float* __restrict__ out)
{
    const int lane = threadIdx.x & 63;
    const int g    = lane & 3;
    const int r    = (blockIdx.x * 256 + threadIdx.x) >> 2;
    if (r >= N_RAYS) return;
    const int s = ray_start[r];
    const int e = ray_start[r + 1];
    const float tmin_r = t_min[r];

    float eT = 1.0f, aR = 0.0f, aG = 0.0f, aB = 0.0f, aD = 0.0f;
    const int niter = (e - s + 3) >> 2;
    for (int it = 0; it < niter; ++it) {
        const int idx = s + it * 4 + g;
        const bool valid = (idx < e);
        const int ci = valid ? idx : (e - 1);
        const float4 res = results[ci];
        const float z = tmin_r + (float)step_id[ci] * STEP_SZ;
        const float elt = valid ? __expf(res.x) : 1.0f;   // exp(lt), 1 => w=0

        // exclusive prefix product of elt within the quad
        float excl = 1.0f;
        const float v1 = __shfl_up(elt, 1, 4); if (g >= 1) excl *= v1;
        const float v2 = __shfl_up(elt, 2, 4); if (g >= 2) excl *= v2;
        const float v3 = __shfl_up(elt, 3, 4); if (g >= 3) excl *= v3;

        const float w = eT * excl * (1.0f - elt);
        aR += w * res.y;
        aG += w * res.z;
        aB += w * res.w;
        aD += w * z;

        const float tot = __shfl(excl * elt, 3, 4);  // product of all 4 elts
        eT *= tot;
    }

    // quad reduction of accumulators
    aR += __shfl_xor(aR, 1); aR += __shfl_xor(aR, 2);
    aG += __shfl_xor(aG, 1); aG += __shfl_xor(aG, 2);
    aB += __shfl_xor(aB, 1); aB += __shfl_xor(aB, 2);
    aD += __shfl_xor(aD, 1); aD += __shfl_xor(aD, 2);

    const float outv = (g == 0) ? aR + eT * bg[0]
                     : (g == 1) ? aG + eT * bg[1]
                     : (g == 2) ? aB + eT * bg[2]
                     : aD;
    out[g * N_RAYS + r] = outv;
    if (g == 0) out[4 * N_RAYS + r] = 1.0f - eT;
}

// ---------------------------------------------------------------------------
// Fallback (ws too small): single fused kernel, original layouts.
// ---------------------------------------------------------------------------
__global__ __launch_bounds__(256) void trivec_render_fallback(
    const float* __restrict__ trivecs, const float* __restrict__ densities,
    const float* __restrict__ colors, const float* __restrict__ gws,
    const float* __restrict__ gwl, const float* __restrict__ t_min,
    const float* __restrict__ bg, const int* __restrict__ gis,
    const int* __restrict__ gil, const int* __restrict__ tenso_id,
    const int* __restrict__ ray_id, const int* __restrict__ step_id,
    float* __restrict__ out)
{
    const int lane = threadIdx.x & 63;
    const int r = blockIdx.x * 4 + (threadIdx.x >> 6);
    if (r >= N_RAYS) return;
    const int c = lane & 15;
    const int g = lane >> 4;
    int lo = 0, hi = N_SAMP;
    while (lo < hi) { int mid = (lo + hi) >> 1; if (ray_id[mid] < r) lo = mid + 1; else hi = mid; }
    const int seg_start = lo;
    hi = N_SAMP;
    while (lo < hi) { int mid = (lo + hi) >> 1; if (ray_id[mid] < r + 1) lo = mid + 1; else hi = mid; }
    const int seg_end = lo;
    const float tmin_r = t_min[r];
    float Tlog = 0.0f, accR = 0.0f, accG = 0.0f, accB = 0.0f, accD = 0.0f;
    const int niter = (seg_end - seg_start + 3) >> 2;
    for (int it = 0; it < niter; ++it) {
        const int n = seg_start + it * 4 + g;
        const bool valid = (n < seg_end);
        const int nc = valid ? n : (seg_end - 1);
        const int tid = tenso_id[nc];
        const float* tv = trivecs + (size_t)tid * 384 + c * 24;
        float f = 1.0f;
        #pragma unroll
        for (int a = 0; a < 3; ++a) {
            const int is = gis[nc*3+a], il = gil[nc*3+a];
            const float wS = gws[nc*3+a], wL = gwl[nc*3+a];
            f *= (tv[a*8+is] * wS + tv[a*8+il] * wL);
        }
        const float dns = densities[(size_t)tid * 16 + c];
        const float* colp = colors + ((size_t)tid * 16 + c) * 3;
        float s0 = f*dns, s1 = f*colp[0], s2 = f*colp[1], s3 = f*colp[2];
        #pragma unroll
        for (int m = 1; m < 16; m <<= 1) {
            s0 += __shfl_xor(s0, m); s1 += __shfl_xor(s1, m);
            s2 += __shfl_xor(s2, m); s3 += __shfl_xor(s3, m);
        }
        float dens = fmaxf(s0, 0.0f) + __logf(1.0f + __expf(-fabsf(s0)));
        const float lt = valid ? (-dens * STEP_SZ) : 0.0f;
        const float alpha = 1.0f - __expf(lt);
        const float rr = 1.0f/(1.0f+__expf(-s1)), gg = 1.0f/(1.0f+__expf(-s2)), bb = 1.0f/(1.0f+__expf(-s3));
        const float z = tmin_r + (float)step_id[nc] * STEP_SZ;
        const float lt0 = __shfl(lt,0), lt1 = __shfl(lt,16), lt2 = __shfl(lt,32), lt3 = __shfl(lt,48);
        float excl = Tlog;
        if (g > 0) excl += lt0;
        if (g > 1) excl += lt1;
        if (g > 2) excl += lt2;
        const float w = alpha * __expf(excl);
        Tlog += lt0 + lt1 + lt2 + lt3;
        accR += w*rr; accG += w*gg; accB += w*bb; accD += w*z;
    }
    accR += __shfl_xor(accR,16); accR += __shfl_xor(accR,32);
    accG += __shfl_xor(accG,16); accG += __shfl_xor(accG,32);
    accB += __shfl_xor(accB,16); accB += __shfl_xor(accB,32);
    accD += __shfl_xor(accD,16); accD += __shfl_xor(accD,32);
    const float bgw = __expf(Tlog);
    if (lane == 0) {
        out[0*N_RAYS+r] = accR + bgw*bg[0];
        out[1*N_RAYS+r] = accG + bgw*bg[1];
        out[2*N_RAYS+r] = accB + bgw*bg[2];
        out[3*N_RAYS+r] = accD;
        out[4*N_RAYS+r] = 1.0f - bgw;
    }
}

extern "C" void kernel_launch(void* const* d_in, const int* in_sizes, int n_in,
                              void* d_out, int out_size, void* d_ws, size_t ws_size,
                              hipStream_t stream) {
    const float* trivecs   = (const float*)d_in[0];
    const float* densities = (const float*)d_in[1];
    const float* colors    = (const float*)d_in[2];
    const float* gws       = (const float*)d_in[3];
    const float* gwl       = (const float*)d_in[4];
    const float* t_min     = (const float*)d_in[5];
    const float* bg        = (const float*)d_in[6];
    const int*   gis       = (const int*)d_in[7];
    const int*   gil       = (const int*)d_in[8];
    const int*   tenso_id  = (const int*)d_in[9];
    const int*   ray_id    = (const int*)d_in[10];
    const int*   step_id   = (const int*)d_in[11];
    float* out = (float*)d_out;

    if (ws_size < (size_t)WS_NEED) {
        trivec_render_fallback<<<(N_RAYS + 3) / 4, 256, 0, stream>>>(
            trivecs, densities, colors, gws, gwl, t_min, bg,
            gis, gil, tenso_id, ray_id, step_id, out);
        return;
    }

    char* ws = (char*)d_ws;
    float4* pack     = (float4*)(ws + OFF_PACK);
    float4* results  = (float4*)(ws + OFF_RESULTS);
    int*    perm     = (int*)(ws + OFF_PERM);
    int*    rt       = (int*)(ws + OFF_RT);
    int*    cursor   = (int*)(ws + OFF_CURSOR);
    int*    starts   = (int*)(ws + OFF_STARTS);
    int*    bsums    = (int*)(ws + OFF_BSUMS);
    int*    flag     = (int*)(ws + OFF_FLAG);
    int*    raystart = (int*)(ws + OFF_RSTART);

    // zero cursor + starts + bsums + flag in one async memset
    hipMemsetAsync(ws + OFF_CURSOR, 0, (OFF_FLAG + 64) - OFF_CURSOR, stream);

    pack_bounds_rank<<<(N_SAMP + 255) / 256, 256, 0, stream>>>(
        tenso_id, ray_id, gis, gil, gws, gwl, cursor, rt, raystart, pack);
    scan_fused<<<NB_SCAN, 256, 0, stream>>>(cursor, starts, bsums, flag);
    finalize_perm<<<(N_SAMP + 255) / 256, 256, 0, stream>>>(
        rt, starts, perm);
    gather_phase<<<(P_TENSO + 3) / 4, 256, 0, stream>>>(
        trivecs, densities, colors, starts, cursor, perm, pack, (float*)results);
    ray_render<<<(N_RAYS * 4 + 255) / 256, 256, 0, stream>>>(
        results, t_min, bg, raystart, step_id, out);
}